// Round 6
// baseline (729.896 us; speedup 1.0000x reference)
//
#include <hip/hip_runtime.h>

// AdjacencyMatrix == 4 chained GEMVs with W^T + diagonal scale:
//   v1 = W[0:1024,:]^T x ; v2 = W^T v1 ; v3 = W^T v2 ;
//   v4[last256] = (W^T v3)[last256] ; out[t] = W[j,j]*v4[j], j=7936+t.
//
// Cross-round model: dur_us = kernels + gaps + ~265 us fixed harness work
// (1 GiB ws poison fill 160us + W restore ~85us + launch). R5 = 445 us.
// Two fits: (A) pure-read ceiling ~4 TB/s, kernels ~180us; (B) ~5us/dispatch
// graph gaps (R2 6-kernel < R4 9-kernel despite more traffic), kernels
// ~135us at 5.3-6 TB/s. Both say: fewer dispatches + drop P round-trip.
// R6: 6 dispatches, direct-atomic writeback (no 128 MB P traffic), NT W
// loads, explicit load-ahead software pipeline in the slab loop.

namespace {
constexpr int N = 8192;
constexpr int NF4 = N / 4;       // 2048 float4 per row
constexpr int IN_N = 1024;
constexpr int OUT_N = 256;
constexpr int BT = 256;

constexpr int B1 = 512;          // pass-1 blocks (1024 rows / 2)
constexpr int R1R = IN_N / B1;   // 2 rows/block
constexpr int B2 = 1024;         // full-W pass blocks
constexpr int R2R = N / B2;      // 8 rows/block -> 256 KB contiguous slab

constexpr size_t OFF_V1 = 0;
constexpr size_t OFF_V2 = 8192;
constexpr size_t OFF_V3 = 16384;
constexpr size_t OFF_V4 = 24576;             // 256 floats
constexpr int ZN = 3 * N + OUT_N;

typedef float f4 __attribute__((ext_vector_type(4)));
}

__global__ void zero_vecs(float* __restrict__ ws) {
  int i = blockIdx.x * blockDim.x + threadIdx.x;
  if (i < ZN) ws[i] = 0.0f;
}

// Block b: rows [b*ROWS, (b+1)*ROWS) of W -- contiguous slab, NT float4
// loads, software-pipelined (row i+1's 8 loads issue before row i's FMAs
// retire). Each thread owns 32 distinct columns; one atomicAdd per column
// per block (cross-block contention only).
template <int ROWS>
__global__ __launch_bounds__(BT) void gemv_slab_at(const float* __restrict__ W,
                                                   const float* __restrict__ vin,
                                                   float* __restrict__ vout) {
  __shared__ float sv[ROWS];
  const int b = blockIdx.x, t = threadIdx.x;
  const int i0 = b * ROWS;
  if (t < ROWS) sv[t] = vin[i0 + t];
  __syncthreads();
  const f4* __restrict__ W4 = reinterpret_cast<const f4*>(W) + (size_t)i0 * NF4;

  f4 acc[8], cur[8];
#pragma unroll
  for (int k = 0; k < 8; ++k) acc[k] = (f4)(0.f);
#pragma unroll
  for (int k = 0; k < 8; ++k)
    cur[k] = __builtin_nontemporal_load(W4 + k * BT + t);

#pragma unroll
  for (int i = 0; i < ROWS - 1; ++i) {
    f4 nxt[8];
    const f4* __restrict__ row = W4 + (size_t)(i + 1) * NF4;
#pragma unroll
    for (int k = 0; k < 8; ++k)
      nxt[k] = __builtin_nontemporal_load(row + k * BT + t);
    const float s = sv[i];
#pragma unroll
    for (int k = 0; k < 8; ++k) acc[k] += cur[k] * s;
#pragma unroll
    for (int k = 0; k < 8; ++k) cur[k] = nxt[k];
  }
  {
    const float s = sv[ROWS - 1];
#pragma unroll
    for (int k = 0; k < 8; ++k) acc[k] += cur[k] * s;
  }
#pragma unroll
  for (int k = 0; k < 8; ++k) {
    const int j = (k * BT + t) * 4;
    atomicAdd(vout + j + 0, acc[k].x);
    atomicAdd(vout + j + 1, acc[k].y);
    atomicAdd(vout + j + 2, acc[k].z);
    atomicAdd(vout + j + 3, acc[k].w);
  }
}

// v4 = (W^T v3) restricted to the last 256 columns (float4 idx 1984..2047).
__global__ __launch_bounds__(64) void gemv_tail(const float* __restrict__ W,
                                                const float* __restrict__ v3,
                                                float* __restrict__ v4) {
  __shared__ float sv[32];
  const int b = blockIdx.x, t = threadIdx.x;
  const int i0 = b * 32;
  if (t < 32) sv[t] = v3[i0 + t];
  __syncthreads();
  const f4* __restrict__ W4 = reinterpret_cast<const f4*>(W);
  f4 a = (f4)(0.f);
#pragma unroll 4
  for (int i = 0; i < 32; ++i) {
    const f4 w = __builtin_nontemporal_load(W4 + (size_t)(i0 + i) * NF4 + 1984 + t);
    a += w * sv[i];
  }
  atomicAdd(v4 + 4 * t + 0, a.x);
  atomicAdd(v4 + 4 * t + 1, a.y);
  atomicAdd(v4 + 4 * t + 2, a.z);
  atomicAdd(v4 + 4 * t + 3, a.w);
}

__global__ void diag_scale(const float* __restrict__ W,
                           const float* __restrict__ v4,
                           float* __restrict__ out) {
  const int t = threadIdx.x;
  const size_t j = (size_t)(N - OUT_N + t);
  out[t] = W[j * (N + 1)] * v4[t];
}

extern "C" void kernel_launch(void* const* d_in, const int* in_sizes, int n_in,
                              void* d_out, int out_size, void* d_ws, size_t ws_size,
                              hipStream_t stream) {
  const float* x = (const float*)d_in[0];   // [1,1024] f32
  const float* W = (const float*)d_in[1];   // [8192,8192] f32 row-major
  // d_in[2] = num_steps == 4 (chain hardcoded)
  float* ws = (float*)d_ws;
  float* v1 = ws + OFF_V1;
  float* v2 = ws + OFF_V2;
  float* v3 = ws + OFF_V3;
  float* v4 = ws + OFF_V4;
  float* out = (float*)d_out;

  // 1) zero the accumulator vectors (ws is poisoned each call)
  zero_vecs<<<(ZN + 255) / 256, 256, 0, stream>>>(ws);
  // 2) v1 = W[0:1024,:]^T x : 512 slabs x 2 rows (32 MB)
  gemv_slab_at<R1R><<<B1, BT, 0, stream>>>(W, x, v1);
  // 3) v2 = W^T v1 : 1024 slabs x 8 rows (268 MB)
  gemv_slab_at<R2R><<<B2, BT, 0, stream>>>(W, v1, v2);
  // 4) v3 = W^T v2
  gemv_slab_at<R2R><<<B2, BT, 0, stream>>>(W, v2, v3);
  // 5) v4 = (W^T v3)[last 256 cols] : 8 MB strip
  gemv_tail<<<N / 32, 64, 0, stream>>>(W, v3, v4);
  // 6) out[t] = W[j,j] * v4[t]
  diag_scale<<<1, OUT_N, 0, stream>>>(W, v4, out);
}

// Round 7
// 461.545 us; speedup vs baseline: 1.5814x; 1.5814x over previous
//
#include <hip/hip_runtime.h>

// AdjacencyMatrix == 4 chained GEMVs with W^T + diagonal scale:
//   v1 = W[0:1024,:]^T x ; v2 = W^T v1 ; v3 = W^T v2 ;
//   v4[last256] = (W^T v3)[last256] ; out[t] = W[j,j]*v4[j], j=7936+t.
//
// Evidence so far:
//  - ~265 us of the timed window is fixed harness work (1 GiB ws poison
//    fill @160us + W restore + launch overhead). Kernel budget is the rest.
//  - R6: device atomicAdd writes THROUGH to HBM (~16B/atomic; 8.4M atomics
//    -> 134 MB WRITE_SIZE, 170us passes at VALUBusy 0.8%). Never bulk-atomic.
//  - R6: FETCH_SIZE of a full-W pass is 134 MB, not 268 -- L3 serves half
//    of W across replays. Reads are healthy; structure overhead is the fat.
// R7: 5 dispatches, zero bulk atomics. Partials P in ws; each consumer
// kernel self-reduces the few v entries it needs in an LDS prologue
// (P is L2/L3-resident), with row-0 W loads issued before the prologue.

namespace {
constexpr int N = 8192;
constexpr int NF4 = N / 4;       // 2048 float4 per row
constexpr int OUT_N = 256;
constexpr int BT = 256;

constexpr int B1 = 256;          // pass-1 blocks: 1024 rows / 4
constexpr int B2 = 1024;         // full-W pass blocks: 8 rows each (256 KB slab)

// ws float offsets
constexpr size_t OFF_V4 = 0;                       // 256 floats
constexpr size_t OFF_P1 = 1024;                    // 256*8192 = 8 MB
constexpr size_t OFF_P2 = OFF_P1 + (size_t)B1 * N; // 1024*8192 = 32 MB
constexpr size_t OFF_P3 = OFF_P2 + (size_t)B2 * N; // 32 MB

typedef float f4 __attribute__((ext_vector_type(4)));
}

// Pass 1: block b handles rows [4b,4b+4) of W (first 1024 rows), scales by
// x, writes an 8192-wide partial to P1[b]. Block 0 also zeroes v4.
__global__ __launch_bounds__(BT) void slab_first(const float* __restrict__ W,
                                                 const float* __restrict__ x,
                                                 float* __restrict__ P1,
                                                 float* __restrict__ v4) {
  const int b = blockIdx.x, t = threadIdx.x;
  if (b == 0) v4[t] = 0.0f;          // ws is poisoned每call; tail atomics need 0
  __shared__ float sv[4];
  const int i0 = b * 4;
  if (t < 4) sv[t] = x[i0 + t];
  __syncthreads();
  const f4* __restrict__ W4 = reinterpret_cast<const f4*>(W) + (size_t)i0 * NF4;
  f4 acc[8];
#pragma unroll
  for (int k = 0; k < 8; ++k) acc[k] = (f4)(0.f);
#pragma unroll
  for (int i = 0; i < 4; ++i) {
    const float s = sv[i];
    const f4* __restrict__ row = W4 + (size_t)i * NF4;
#pragma unroll
    for (int k = 0; k < 8; ++k)
      acc[k] += __builtin_nontemporal_load(row + k * BT + t) * s;
  }
  f4* __restrict__ P4 = reinterpret_cast<f4*>(P1) + (size_t)b * NF4;
#pragma unroll
  for (int k = 0; k < 8; ++k) P4[k * BT + t] = acc[k];
}

// Middle passes: block b self-reduces v[8b..8b+8) from Pin (NPART partials),
// then streams rows [8b,8b+8) of W (contiguous 256 KB slab, NT loads,
// load-ahead pipeline), writes partial to Pout[b].
template <int NPART>
__global__ __launch_bounds__(BT) void slab_mid(const float* __restrict__ W,
                                               const float* __restrict__ Pin,
                                               float* __restrict__ Pout) {
  const int b = blockIdx.x, t = threadIdx.x;
  const int i0 = b * 8;
  const f4* __restrict__ W4 = reinterpret_cast<const f4*>(W) + (size_t)i0 * NF4;

  // Issue row-0 loads first; they drain while we do the LDS prologue.
  f4 cur[8];
#pragma unroll
  for (int k = 0; k < 8; ++k)
    cur[k] = __builtin_nontemporal_load(W4 + k * BT + t);

  // Self-reduce the 8 needed v entries from Pin (L2/L3-resident).
  __shared__ float lds[BT];
  __shared__ float sv[8];
  {
    const int r = t & 7, g = t >> 3;          // 32 c-groups
    float a = 0.f;
#pragma unroll 4
    for (int it = 0; it < NPART / 32; ++it)
      a += Pin[(size_t)(g + 32 * it) * N + i0 + r];
    lds[t] = a;
    __syncthreads();
    if (t < 8) {
      float s = 0.f;
#pragma unroll
      for (int g2 = 0; g2 < 32; ++g2) s += lds[g2 * 8 + t];
      sv[t] = s;
    }
    __syncthreads();
  }

  f4 acc[8];
#pragma unroll
  for (int k = 0; k < 8; ++k) acc[k] = (f4)(0.f);
#pragma unroll
  for (int i = 0; i < 7; ++i) {
    f4 nxt[8];
    const f4* __restrict__ row = W4 + (size_t)(i + 1) * NF4;
#pragma unroll
    for (int k = 0; k < 8; ++k)
      nxt[k] = __builtin_nontemporal_load(row + k * BT + t);
    const float s = sv[i];
#pragma unroll
    for (int k = 0; k < 8; ++k) acc[k] += cur[k] * s;
#pragma unroll
    for (int k = 0; k < 8; ++k) cur[k] = nxt[k];
  }
  const float s7 = sv[7];
#pragma unroll
  for (int k = 0; k < 8; ++k) acc[k] += cur[k] * s7;

  f4* __restrict__ P4 = reinterpret_cast<f4*>(Pout) + (size_t)b * NF4;
#pragma unroll
  for (int k = 0; k < 8; ++k) P4[k * BT + t] = acc[k];
}

// Tail: block b self-reduces v3[32b..32b+32) from P3, then contracts the
// last-256-column strip of rows [32b,32b+32); LDS-combines; 65K atomics
// total into v4 (negligible write-through).
__global__ __launch_bounds__(BT) void gemv_tail(const float* __restrict__ W,
                                                const float* __restrict__ P3,
                                                float* __restrict__ v4) {
  const int b = blockIdx.x, t = threadIdx.x;
  const int i0 = b * 32;
  __shared__ float lds[BT];
  __shared__ float sv[32];
  __shared__ f4 lds4[BT];
  {
    const int r = t & 31, g = t >> 5;         // 8 c-groups of 128
    float a = 0.f;
#pragma unroll 4
    for (int it = 0; it < 128; ++it)
      a += P3[(size_t)(g + 8 * it) * N + i0 + r];
    lds[t] = a;
    __syncthreads();
    if (t < 32) {
      float s = 0.f;
#pragma unroll
      for (int g2 = 0; g2 < 8; ++g2) s += lds[g2 * 32 + t];
      sv[t] = s;
    }
    __syncthreads();
  }
  const f4* __restrict__ W4 = reinterpret_cast<const f4*>(W);
  const int c4 = t & 63;                      // strip float4 1984+c4
  const int rr = t >> 6;                      // 4 row-groups of 8
  f4 a = (f4)(0.f);
#pragma unroll
  for (int i = 0; i < 8; ++i) {
    const int row = i0 + rr * 8 + i;
    const f4 w = __builtin_nontemporal_load(W4 + (size_t)row * NF4 + 1984 + c4);
    a += w * sv[rr * 8 + i];
  }
  lds4[t] = a;
  __syncthreads();
  if (t < 64) {
    f4 s = lds4[t] + lds4[64 + t] + lds4[128 + t] + lds4[192 + t];
    atomicAdd(v4 + 4 * t + 0, s.x);
    atomicAdd(v4 + 4 * t + 1, s.y);
    atomicAdd(v4 + 4 * t + 2, s.z);
    atomicAdd(v4 + 4 * t + 3, s.w);
  }
}

__global__ void diag_scale(const float* __restrict__ W,
                           const float* __restrict__ v4,
                           float* __restrict__ out) {
  const int t = threadIdx.x;
  const size_t j = (size_t)(N - OUT_N + t);
  out[t] = W[j * (N + 1)] * v4[t];
}

extern "C" void kernel_launch(void* const* d_in, const int* in_sizes, int n_in,
                              void* d_out, int out_size, void* d_ws, size_t ws_size,
                              hipStream_t stream) {
  const float* x = (const float*)d_in[0];   // [1,1024] f32
  const float* W = (const float*)d_in[1];   // [8192,8192] f32 row-major
  // d_in[2] = num_steps == 4 (chain hardcoded)
  float* ws = (float*)d_ws;
  float* v4 = ws + OFF_V4;
  float* P1 = ws + OFF_P1;
  float* P2 = ws + OFF_P2;
  float* P3 = ws + OFF_P3;
  float* out = (float*)d_out;

  // 1) v1-partials from W[0:1024,:] (32 MB) ; also zeroes v4
  slab_first<<<B1, BT, 0, stream>>>(W, x, P1, v4);
  // 2) v2-partials: self-reduce v1 from P1, stream full W (268 MB)
  slab_mid<B1><<<B2, BT, 0, stream>>>(W, P1, P2);
  // 3) v3-partials: self-reduce v2 from P2, stream full W
  slab_mid<B2><<<B2, BT, 0, stream>>>(W, P2, P3);
  // 4) v4 = (W^T v3)[last 256 cols]: self-reduce v3 from P3 + 8 MB strip
  gemv_tail<<<N / 32, BT, 0, stream>>>(W, P3, v4);
  // 5) out[t] = W[j,j] * v4[t]
  diag_scale<<<1, OUT_N, 0, stream>>>(W, v4, out);
}